// Round 7
// baseline (322.687 us; speedup 1.0000x reference)
//
#include <hip/hip_runtime.h>
#include <hip/hip_bf16.h>
#include <hip/hip_fp16.h>

#define HID 128
#define NCLS 16
#define NGRAPH 64
#define CHUNK 1024

using bf16x8 = __attribute__((ext_vector_type(8))) short;
using f32x4  = __attribute__((ext_vector_type(4))) float;

// round-to-nearest-even f32 -> bf16
__device__ __forceinline__ unsigned int f2bf(float f) {
    unsigned int u = __float_as_uint(f);
    return (u + 0x7FFFu + ((u >> 16) & 1u)) >> 16;
}
__device__ __forceinline__ float bf2f_lo(unsigned int u) { return __uint_as_float(u << 16); }
__device__ __forceinline__ float bf2f_hi(unsigned int u) { return __uint_as_float(u & 0xFFFF0000u); }

// ---------------- init: zero accumulators + W prep (fused) ----------------
// Wt[m][col*128+k] = bf16(W[m][k*128+col])
__global__ __launch_bounds__(256) void k_init(int* counts, float* pooled, float* cnt,
                                              const float* __restrict__ W0,
                                              const float* __restrict__ W1,
                                              const float* __restrict__ W2,
                                              unsigned short* __restrict__ Wt, int n) {
    int i = blockIdx.x * 256 + threadIdx.x;
    if (i < n) counts[i] = 0;
    if (i < NGRAPH * HID) pooled[i] = 0.0f;
    if (i < NGRAPH) cnt[i] = 0.0f;
    if (i < 3 * HID * HID) {
        int m = i >> 14;
        int r = i & 16383;
        int c = r >> 7, k = r & 127;
        const float* W = (m == 0) ? W0 : (m == 1) ? W1 : W2;
        Wt[i] = (unsigned short)f2bf(W[k * HID + c]);
    }
}

// ---------------- degree histogram over dst + per-edge rank ----------------
__global__ __launch_bounds__(256) void k_hist(const int* __restrict__ dst,
                                              int* counts, int* rank, int e) {
    int i = blockIdx.x * 256 + threadIdx.x;
    if (i < e) rank[i] = atomicAdd(&counts[dst[i]], 1);
}

// ---------------- scan step 1: per-chunk sums ----------------
__global__ __launch_bounds__(256) void k_chunksum(const int* __restrict__ counts,
                                                  int* csum, int n) {
    __shared__ int sdata[256];
    int b = blockIdx.x, t = threadIdx.x;
    int base = b * CHUNK + t * 4;
    int s = 0;
    #pragma unroll
    for (int j = 0; j < 4; ++j) { int i = base + j; if (i < n) s += counts[i]; }
    sdata[t] = s; __syncthreads();
    for (int off = 128; off > 0; off >>= 1) {
        if (t < off) sdata[t] += sdata[t + off];
        __syncthreads();
    }
    if (t == 0) csum[b] = sdata[0];
}

// ---------------- rowptr: per-chunk exclusive scan (chunk offset computed in-block) ----------------
__global__ __launch_bounds__(256) void k_rowptr(const int* __restrict__ counts,
                                                const int* __restrict__ csum,
                                                int* rowptr, int n, int e) {
    __shared__ int sincl[256];
    __shared__ int s_coff;
    int b = blockIdx.x, t = threadIdx.x;
    // sum csum[0..b-1] with wave 0 (NB <= 64)
    if (t < 64) {
        int v = (t < b) ? csum[t] : 0;
        #pragma unroll
        for (int off = 32; off > 0; off >>= 1) v += __shfl_xor(v, off);
        if (t == 0) s_coff = v;
    }
    int base = b * CHUNK + t * 4;
    int v[4]; int s = 0;
    #pragma unroll
    for (int j = 0; j < 4; ++j) { int i = base + j; v[j] = (i < n) ? counts[i] : 0; s += v[j]; }
    sincl[t] = s; __syncthreads();
    for (int off = 1; off < 256; off <<= 1) {
        int x = sincl[t];
        int y = (t >= off) ? sincl[t - off] : 0;
        __syncthreads();
        sincl[t] = x + y;
        __syncthreads();
    }
    int run = s_coff + sincl[t] - s;
    #pragma unroll
    for (int j = 0; j < 4; ++j) {
        int i = base + j;
        if (i < n) { rowptr[i] = run; run += v[j]; }
    }
    if (b == 0 && t == 0) rowptr[n] = e;
}

// ---------------- CSR fill: 4B records {u16 src | fp16 norm}, no atomics ----------------
__global__ __launch_bounds__(256) void k_fill(const int* __restrict__ src,
                                              const int* __restrict__ dst,
                                              const int* __restrict__ rank,
                                              const int* __restrict__ counts,
                                              const int* __restrict__ rowptr,
                                              unsigned int* __restrict__ epk, int e) {
    int i = blockIdx.x * 256 + threadIdx.x;
    if (i >= e) return;
    int s = src[i], d = dst[i];
    int pos = rowptr[d] + rank[i];
    float norm = rsqrtf((float)(counts[s] + 1)) * rsqrtf((float)(counts[d] + 1));
    __half h = __float2half(norm);
    unsigned int hu = (unsigned int)__half_as_ushort(h);
    epk[pos] = (unsigned int)s | (hu << 16);
}

// ---------------- MFMA GEMM (f32 input, layer 0) -> split half-tables ----------------
__global__ __launch_bounds__(256) void k_gemm_f32(const float* __restrict__ H,
                                                  const unsigned short* __restrict__ Wt,
                                                  unsigned short* __restrict__ Tlo,
                                                  unsigned short* __restrict__ Thi, int n) {
    __shared__ char ldsA[64 * 256];
    int t = threadIdx.x;
    int cg = t & 31;
    int rg = t >> 5;
    int row0 = blockIdx.x * 64;

    #pragma unroll
    for (int i = 0; i < 8; ++i) {
        int lr = rg + i * 8;
        int r = row0 + lr;
        float4 v = make_float4(0.f, 0.f, 0.f, 0.f);
        if (r < n) v = ((const float4*)H)[(size_t)r * 32 + cg];
        uint2 pk;
        pk.x = f2bf(v.x) | (f2bf(v.y) << 16);
        pk.y = f2bf(v.z) | (f2bf(v.w) << 16);
        int byte = lr * 256 + cg * 8;
        *(uint2*)(ldsA + (byte ^ ((lr & 7) << 4))) = pk;
    }
    __syncthreads();

    int lane = t & 63;
    int w = t >> 6;
    int rsub = lane & 15;
    int kg = lane >> 4;
    int rowIdx = w * 16 + rsub;
    int abase = rowIdx * 256 + kg * 16;
    int aswz = (rowIdx & 7) << 4;

    f32x4 acc[8];
    #pragma unroll
    for (int nt = 0; nt < 8; ++nt) acc[nt] = (f32x4)(0.f);

    #pragma unroll
    for (int kk = 0; kk < 4; ++kk) {
        bf16x8 a = *(const bf16x8*)(ldsA + ((abase + kk * 64) ^ aswz));
        int k0 = kk * 32 + kg * 8;
        #pragma unroll
        for (int nt = 0; nt < 8; ++nt) {
            int col = nt * 16 + rsub;
            bf16x8 b = *(const bf16x8*)(Wt + col * 128 + k0);
            acc[nt] = __builtin_amdgcn_mfma_f32_16x16x32_bf16(a, b, acc[nt], 0, 0, 0);
        }
    }

    // C/D layout: col = lane&15, row = (lane>>4)*4 + reg
    #pragma unroll
    for (int nt = 0; nt < 8; ++nt) {
        unsigned short* Tb = (nt < 4) ? Tlo : Thi;
        #pragma unroll
        for (int j = 0; j < 4; ++j) {
            int row = row0 + w * 16 + kg * 4 + j;
            int col = (nt * 16 + rsub) & 63;
            if (row < n) Tb[(size_t)row * 64 + col] = (unsigned short)f2bf(acc[nt][j]);
        }
    }
}

// ---------------- MFMA GEMM (bf16 split input, layers 1/2) ----------------
__global__ __launch_bounds__(256) void k_gemm_bf16(const unsigned short* __restrict__ Hlo,
                                                   const unsigned short* __restrict__ Hhi,
                                                   const unsigned short* __restrict__ Wt,
                                                   unsigned short* __restrict__ Tlo,
                                                   unsigned short* __restrict__ Thi, int n) {
    __shared__ char ldsA[64 * 256];
    int t = threadIdx.x;
    int row0 = blockIdx.x * 64;
    int c16 = t & 15;             // 16B chunk within 256B row
    int rbase = t >> 4;           // 0..15

    #pragma unroll
    for (int i = 0; i < 4; ++i) {
        int lr = rbase + i * 16;
        int r = row0 + lr;
        const unsigned short* Hb = (c16 < 8) ? Hlo : Hhi;
        uint4 v = make_uint4(0u, 0u, 0u, 0u);
        if (r < n) v = *(const uint4*)(Hb + (size_t)r * 64 + (c16 & 7) * 8);
        int byte = lr * 256 + c16 * 16;
        *(uint4*)(ldsA + (byte ^ ((lr & 7) << 4))) = v;
    }
    __syncthreads();

    int lane = t & 63;
    int w = t >> 6;
    int rsub = lane & 15;
    int kg = lane >> 4;
    int rowIdx = w * 16 + rsub;
    int abase = rowIdx * 256 + kg * 16;
    int aswz = (rowIdx & 7) << 4;

    f32x4 acc[8];
    #pragma unroll
    for (int nt = 0; nt < 8; ++nt) acc[nt] = (f32x4)(0.f);

    #pragma unroll
    for (int kk = 0; kk < 4; ++kk) {
        bf16x8 a = *(const bf16x8*)(ldsA + ((abase + kk * 64) ^ aswz));
        int k0 = kk * 32 + kg * 8;
        #pragma unroll
        for (int nt = 0; nt < 8; ++nt) {
            int col = nt * 16 + rsub;
            bf16x8 b = *(const bf16x8*)(Wt + col * 128 + k0);
            acc[nt] = __builtin_amdgcn_mfma_f32_16x16x32_bf16(a, b, acc[nt], 0, 0, 0);
        }
    }

    #pragma unroll
    for (int nt = 0; nt < 8; ++nt) {
        unsigned short* Tb = (nt < 4) ? Tlo : Thi;
        #pragma unroll
        for (int j = 0; j < 4; ++j) {
            int row = row0 + w * 16 + kg * 4 + j;
            int col = (nt * 16 + rsub) & 63;
            if (row < n) Tb[(size_t)row * 64 + col] = (unsigned short)f2bf(acc[nt][j]);
        }
    }
}

// ---------------- pull aggregation over ONE half-table (64 features = 32 u32) ----------------
// one wave per node: p = lane&31 (feature pair), g = lane>>5 (edge parity).
// Group g handles edges j0 + 2*jj + g; broadcast within the 32-lane group;
// final shfl_xor(32) combines the two parity partial sums.
// mode 0: write relu'd bf16 half-row. mode 1: write f32 (offset hoff float2).
__global__ __launch_bounds__(256) void k_agg_h(const unsigned int* __restrict__ TbH,
                                               unsigned int* __restrict__ outB,
                                               float* __restrict__ outF,
                                               const int* __restrict__ rowptr,
                                               const unsigned int* __restrict__ epk,
                                               const float* __restrict__ biasH,
                                               int n, int mode, int hoff) {
    int wid = (blockIdx.x * 256 + threadIdx.x) >> 6;
    int lane = threadIdx.x & 63;
    if (wid >= n) return;
    int p = lane & 31;
    int g = lane >> 5;
    int start = rowptr[wid];
    int deg = rowptr[wid + 1] - start;

    float2 acc = make_float2(0.f, 0.f);
    if (g == 0) {
        float sn = 1.0f / (float)(deg + 1);     // dinv[i]^2 = 1/(deg+1)
        unsigned int us = TbH[(size_t)wid * 32 + p];
        float2 b2 = ((const float2*)biasH)[p];
        acc.x = fmaf(bf2f_lo(us), sn, b2.x);
        acc.y = fmaf(bf2f_hi(us), sn, b2.y);
    }

    int gbase = g * 32;
    for (int j0 = 0; j0 < deg; j0 += 64) {
        int myj = j0 + 2 * p + g;
        unsigned int rec = 0;
        if (myj < deg) rec = epk[start + myj];
        int rem = deg - j0 - g;                  // >= 0 here
        int mg = min(32, (rem + 1) >> 1);        // edges this group this block
        int jj = 0;
        for (; jj + 8 <= mg; jj += 8) {
            unsigned int rr[8], uu[8];
            #pragma unroll
            for (int k = 0; k < 8; ++k) rr[k] = (unsigned int)__shfl((int)rec, gbase + jj + k);
            #pragma unroll
            for (int k = 0; k < 8; ++k) uu[k] = TbH[(size_t)(rr[k] & 0xFFFFu) * 32 + p];
            #pragma unroll
            for (int k = 0; k < 8; ++k) {
                float wk = __half2float(__ushort_as_half((unsigned short)(rr[k] >> 16)));
                acc.x = fmaf(wk, bf2f_lo(uu[k]), acc.x);
                acc.y = fmaf(wk, bf2f_hi(uu[k]), acc.y);
            }
        }
        for (; jj < mg; ++jj) {
            unsigned int rj = (unsigned int)__shfl((int)rec, gbase + jj);
            unsigned int u = TbH[(size_t)(rj & 0xFFFFu) * 32 + p];
            float wj = __half2float(__ushort_as_half((unsigned short)(rj >> 16)));
            acc.x = fmaf(wj, bf2f_lo(u), acc.x);
            acc.y = fmaf(wj, bf2f_hi(u), acc.y);
        }
    }

    // combine parity groups
    acc.x += __shfl_xor(acc.x, 32);
    acc.y += __shfl_xor(acc.y, 32);

    if (g == 0) {
        if (mode == 0) {
            float rx = fmaxf(acc.x, 0.f), ry = fmaxf(acc.y, 0.f);
            outB[(size_t)wid * 32 + p] = f2bf(rx) | (f2bf(ry) << 16);
        } else {
            ((float2*)outF)[(size_t)wid * 64 + hoff + p] = acc;
        }
    }
}

// ---------------- pooling: segment-sum over sorted batch ids ----------------
__global__ __launch_bounds__(256) void k_pool(const float* __restrict__ H,
                                              const int* __restrict__ batch,
                                              float* pooled, float* cnt, int n) {
    int gw = (blockIdx.x * 256 + threadIdx.x) >> 6;
    int lane = threadIdx.x & 63;
    int n0 = gw * 32;
    if (n0 >= n) return;
    int n1 = min(n0 + 32, n);
    const float2* H2 = (const float2*)H;
    int gprev = batch[n0];
    float2 acc = make_float2(0.f, 0.f);
    float runc = 0.f;
    for (int i = n0; i < n1; ++i) {
        int g = batch[i];
        if (g != gprev) {
            atomicAdd(&pooled[gprev * HID + 2 * lane], acc.x);
            atomicAdd(&pooled[gprev * HID + 2 * lane + 1], acc.y);
            if (lane == 0) atomicAdd(&cnt[gprev], runc);
            acc = make_float2(0.f, 0.f); runc = 0.f; gprev = g;
        }
        float2 v = H2[(size_t)i * 64 + lane];
        acc.x += v.x; acc.y += v.y; runc += 1.f;
    }
    atomicAdd(&pooled[gprev * HID + 2 * lane], acc.x);
    atomicAdd(&pooled[gprev * HID + 2 * lane + 1], acc.y);
    if (lane == 0) atomicAdd(&cnt[gprev], runc);
}

// ---------------- head ----------------
__global__ __launch_bounds__(256) void k_head(const float* __restrict__ pooled,
                                              const float* __restrict__ cnt,
                                              const float* __restrict__ Wc,
                                              const float* __restrict__ bc,
                                              float* __restrict__ out) {
    int idx = blockIdx.x * 256 + threadIdx.x;
    if (idx >= NGRAPH * NCLS) return;
    int g = idx >> 4, c = idx & 15;
    float inv = 1.0f / fmaxf(cnt[g], 1.0f);
    float s = 0.f;
    for (int k = 0; k < HID; ++k)
        s = fmaf(pooled[g * HID + k], Wc[k * NCLS + c], s);
    out[idx] = s * inv + bc[c];
}

extern "C" void kernel_launch(void* const* d_in, const int* in_sizes, int n_in,
                              void* d_out, int out_size, void* d_ws, size_t ws_size,
                              hipStream_t stream) {
    const float* x    = (const float*)d_in[0];
    const int*   ei   = (const int*)d_in[1];
    const int*   batch= (const int*)d_in[2];
    const float* W0   = (const float*)d_in[3];
    const float* b0   = (const float*)d_in[4];
    const float* W1   = (const float*)d_in[5];
    const float* b1   = (const float*)d_in[6];
    const float* W2   = (const float*)d_in[7];
    const float* b2   = (const float*)d_in[8];
    const float* Wc   = (const float*)d_in[9];
    const float* bc   = (const float*)d_in[10];
    float* out = (float*)d_out;

    const int N = in_sizes[0] / HID;       // 50000
    const int E = in_sizes[1] / 2;         // 800000
    const int* src = ei;
    const int* dst = ei + E;

    char* p = (char*)d_ws;
    auto alloc = [&](size_t bytes) { void* r = (void*)p; p += (bytes + 255) & ~(size_t)255; return r; };
    int*   counts = (int*)alloc((size_t)N * 4);
    int*   rank   = (int*)alloc((size_t)E * 4);
    int*   csum   = (int*)alloc(256 * 4);
    int*   rowptr = (int*)alloc((size_t)(N + 1) * 4);
    unsigned int* epk = (unsigned int*)alloc((size_t)E * 4);
    float* pooled = (float*)alloc((size_t)NGRAPH * HID * 4);
    float* cnt    = (float*)alloc((size_t)NGRAPH * 4);
    unsigned short* Tlo = (unsigned short*)alloc((size_t)N * 64 * 2);
    unsigned short* Thi = (unsigned short*)alloc((size_t)N * 64 * 2);
    unsigned short* Hlo = (unsigned short*)alloc((size_t)N * 64 * 2);
    unsigned short* Hhi = (unsigned short*)alloc((size_t)N * 64 * 2);
    float* bufF   = (float*)alloc((size_t)N * HID * 4);
    unsigned short* Wt = (unsigned short*)alloc((size_t)3 * HID * HID * 2);

    const int NB = (N + CHUNK - 1) / CHUNK;

    k_init<<<(N + 255) / 256, 256, 0, stream>>>(counts, pooled, cnt, W0, W1, W2, Wt, N);
    k_hist<<<(E + 255) / 256, 256, 0, stream>>>(dst, counts, rank, E);
    k_chunksum<<<NB, 256, 0, stream>>>(counts, csum, N);
    k_rowptr<<<NB, 256, 0, stream>>>(counts, csum, rowptr, N, E);
    k_fill<<<(E + 255) / 256, 256, 0, stream>>>(src, dst, rank, counts, rowptr, epk, E);

    const int gemm_grid = (N + 63) / 64;
    const int agg_grid  = ((size_t)N * 64 + 255) / 256;

    // layer 0
    k_gemm_f32<<<gemm_grid, 256, 0, stream>>>(x, Wt, Tlo, Thi, N);
    k_agg_h<<<agg_grid, 256, 0, stream>>>((const unsigned int*)Tlo, (unsigned int*)Hlo, nullptr,
                                          rowptr, epk, b0, N, 0, 0);
    k_agg_h<<<agg_grid, 256, 0, stream>>>((const unsigned int*)Thi, (unsigned int*)Hhi, nullptr,
                                          rowptr, epk, b0 + 64, N, 0, 32);
    // layer 1
    k_gemm_bf16<<<gemm_grid, 256, 0, stream>>>(Hlo, Hhi, Wt + 16384, Tlo, Thi, N);
    k_agg_h<<<agg_grid, 256, 0, stream>>>((const unsigned int*)Tlo, (unsigned int*)Hlo, nullptr,
                                          rowptr, epk, b1, N, 0, 0);
    k_agg_h<<<agg_grid, 256, 0, stream>>>((const unsigned int*)Thi, (unsigned int*)Hhi, nullptr,
                                          rowptr, epk, b1 + 64, N, 0, 32);
    // layer 2
    k_gemm_bf16<<<gemm_grid, 256, 0, stream>>>(Hlo, Hhi, Wt + 32768, Tlo, Thi, N);
    k_agg_h<<<agg_grid, 256, 0, stream>>>((const unsigned int*)Tlo, nullptr, bufF,
                                          rowptr, epk, b2, N, 1, 0);
    k_agg_h<<<agg_grid, 256, 0, stream>>>((const unsigned int*)Thi, nullptr, bufF,
                                          rowptr, epk, b2 + 64, N, 1, 32);

    // pooling + head
    const int pool_waves = (N + 31) / 32;
    k_pool<<<(pool_waves * 64 + 255) / 256, 256, 0, stream>>>(bufF, batch, pooled, cnt, N);
    k_head<<<(NGRAPH * NCLS + 255) / 256, 256, 0, stream>>>(pooled, cnt, Wc, bc, out);
}

// Round 8
// 236.817 us; speedup vs baseline: 1.3626x; 1.3626x over previous
//
#include <hip/hip_runtime.h>
#include <hip/hip_bf16.h>
#include <hip/hip_fp16.h>

#define HID 128
#define NCLS 16
#define NGRAPH 64
#define CHUNK 1024

using bf16x8 = __attribute__((ext_vector_type(8))) short;
using f32x4  = __attribute__((ext_vector_type(4))) float;

// round-to-nearest-even f32 -> bf16
__device__ __forceinline__ unsigned int f2bf(float f) {
    unsigned int u = __float_as_uint(f);
    return (u + 0x7FFFu + ((u >> 16) & 1u)) >> 16;
}
__device__ __forceinline__ float bf2f_lo(unsigned int u) { return __uint_as_float(u << 16); }
__device__ __forceinline__ float bf2f_hi(unsigned int u) { return __uint_as_float(u & 0xFFFF0000u); }

// ---------------- init: zero accumulators + W0/W1 prep (fused) ----------------
// Wt[m][col*128+k] = bf16(W[m][k*128+col]) for m in {0,1}
__global__ __launch_bounds__(256) void k_init(int* counts, float* pooled, float* cnt,
                                              const float* __restrict__ W0,
                                              const float* __restrict__ W1,
                                              unsigned short* __restrict__ Wt, int n) {
    int i = blockIdx.x * 256 + threadIdx.x;
    if (i < n) counts[i] = 0;
    if (i < NGRAPH * NCLS) pooled[i] = 0.0f;
    if (i < NGRAPH) cnt[i] = 0.0f;
    if (i < 2 * HID * HID) {
        int m = i >> 14;
        int r = i & 16383;
        int c = r >> 7, k = r & 127;
        const float* W = (m == 0) ? W0 : W1;
        Wt[i] = (unsigned short)f2bf(W[k * HID + c]);
    }
}

// ---------------- W2@Wc fold: Wt2c[c*128+k] = bf16(sum_j W2[k,j]*Wc[j,c]); bc2 = b2@Wc + bc ----------------
__global__ __launch_bounds__(256) void k_wc(const float* __restrict__ W2,
                                            const float* __restrict__ Wc,
                                            const float* __restrict__ b2,
                                            const float* __restrict__ bcin,
                                            unsigned short* __restrict__ Wt2c,
                                            float* __restrict__ bc2) {
    int tid = blockIdx.x * 256 + threadIdx.x;
    if (tid < HID * NCLS) {
        int k = tid >> 4, c = tid & 15;
        float s = 0.f;
        #pragma unroll 8
        for (int j = 0; j < HID; ++j)
            s = fmaf(W2[k * HID + j], Wc[j * NCLS + c], s);
        Wt2c[c * 128 + k] = (unsigned short)f2bf(s);
    }
    if (tid < NCLS) {
        float s = 0.f;
        for (int j = 0; j < HID; ++j)
            s = fmaf(b2[j], Wc[j * NCLS + tid], s);
        bc2[tid] = s + bcin[tid];
    }
}

// ---------------- degree histogram over dst + per-edge rank ----------------
__global__ __launch_bounds__(256) void k_hist(const int* __restrict__ dst,
                                              int* counts, int* rank, int e) {
    int i = blockIdx.x * 256 + threadIdx.x;
    if (i < e) rank[i] = atomicAdd(&counts[dst[i]], 1);
}

// ---------------- scan step 1: per-chunk sums ----------------
__global__ __launch_bounds__(256) void k_chunksum(const int* __restrict__ counts,
                                                  int* csum, int n) {
    __shared__ int sdata[256];
    int b = blockIdx.x, t = threadIdx.x;
    int base = b * CHUNK + t * 4;
    int s = 0;
    #pragma unroll
    for (int j = 0; j < 4; ++j) { int i = base + j; if (i < n) s += counts[i]; }
    sdata[t] = s; __syncthreads();
    for (int off = 128; off > 0; off >>= 1) {
        if (t < off) sdata[t] += sdata[t + off];
        __syncthreads();
    }
    if (t == 0) csum[b] = sdata[0];
}

// ---------------- rowptr: per-chunk exclusive scan (chunk offset in-block) ----------------
__global__ __launch_bounds__(256) void k_rowptr(const int* __restrict__ counts,
                                                const int* __restrict__ csum,
                                                int* rowptr, int n, int e) {
    __shared__ int sincl[256];
    __shared__ int s_coff;
    int b = blockIdx.x, t = threadIdx.x;
    if (t < 64) {
        int v = (t < b) ? csum[t] : 0;
        #pragma unroll
        for (int off = 32; off > 0; off >>= 1) v += __shfl_xor(v, off);
        if (t == 0) s_coff = v;
    }
    int base = b * CHUNK + t * 4;
    int v[4]; int s = 0;
    #pragma unroll
    for (int j = 0; j < 4; ++j) { int i = base + j; v[j] = (i < n) ? counts[i] : 0; s += v[j]; }
    sincl[t] = s; __syncthreads();
    for (int off = 1; off < 256; off <<= 1) {
        int x = sincl[t];
        int y = (t >= off) ? sincl[t - off] : 0;
        __syncthreads();
        sincl[t] = x + y;
        __syncthreads();
    }
    int run = s_coff + sincl[t] - s;
    #pragma unroll
    for (int j = 0; j < 4; ++j) {
        int i = base + j;
        if (i < n) { rowptr[i] = run; run += v[j]; }
    }
    if (b == 0 && t == 0) rowptr[n] = e;
}

// ---------------- CSR fill: 4B records {u16 src | fp16 norm}, no atomics ----------------
__global__ __launch_bounds__(256) void k_fill(const int* __restrict__ src,
                                              const int* __restrict__ dst,
                                              const int* __restrict__ rank,
                                              const int* __restrict__ counts,
                                              const int* __restrict__ rowptr,
                                              unsigned int* __restrict__ epk, int e) {
    int i = blockIdx.x * 256 + threadIdx.x;
    if (i >= e) return;
    int s = src[i], d = dst[i];
    int pos = rowptr[d] + rank[i];
    float norm = rsqrtf((float)(counts[s] + 1)) * rsqrtf((float)(counts[d] + 1));
    __half h = __float2half(norm);
    unsigned int hu = (unsigned int)__half_as_ushort(h);
    epk[pos] = (unsigned int)s | (hu << 16);
}

// ---------------- MFMA GEMM (f32 input, layer 0) ----------------
__global__ __launch_bounds__(256) void k_gemm_f32(const float* __restrict__ H,
                                                  const unsigned short* __restrict__ Wt,
                                                  unsigned short* __restrict__ Tb16, int n) {
    __shared__ char ldsA[64 * 256];
    int t = threadIdx.x;
    int cg = t & 31;
    int rg = t >> 5;
    int row0 = blockIdx.x * 64;

    #pragma unroll
    for (int i = 0; i < 8; ++i) {
        int lr = rg + i * 8;
        int r = row0 + lr;
        float4 v = make_float4(0.f, 0.f, 0.f, 0.f);
        if (r < n) v = ((const float4*)H)[(size_t)r * 32 + cg];
        uint2 pk;
        pk.x = f2bf(v.x) | (f2bf(v.y) << 16);
        pk.y = f2bf(v.z) | (f2bf(v.w) << 16);
        int byte = lr * 256 + cg * 8;
        *(uint2*)(ldsA + (byte ^ ((lr & 7) << 4))) = pk;
    }
    __syncthreads();

    int lane = t & 63;
    int w = t >> 6;
    int rsub = lane & 15;
    int kg = lane >> 4;
    int rowIdx = w * 16 + rsub;
    int abase = rowIdx * 256 + kg * 16;
    int aswz = (rowIdx & 7) << 4;

    f32x4 acc[8];
    #pragma unroll
    for (int nt = 0; nt < 8; ++nt) acc[nt] = (f32x4)(0.f);

    #pragma unroll
    for (int kk = 0; kk < 4; ++kk) {
        bf16x8 a = *(const bf16x8*)(ldsA + ((abase + kk * 64) ^ aswz));
        int k0 = kk * 32 + kg * 8;
        #pragma unroll
        for (int nt = 0; nt < 8; ++nt) {
            int col = nt * 16 + rsub;
            bf16x8 b = *(const bf16x8*)(Wt + col * 128 + k0);
            acc[nt] = __builtin_amdgcn_mfma_f32_16x16x32_bf16(a, b, acc[nt], 0, 0, 0);
        }
    }

    // C/D layout: col = lane&15, row = (lane>>4)*4 + reg
    #pragma unroll
    for (int nt = 0; nt < 8; ++nt) {
        #pragma unroll
        for (int j = 0; j < 4; ++j) {
            int row = row0 + w * 16 + kg * 4 + j;
            int col = nt * 16 + rsub;
            if (row < n) Tb16[(size_t)row * 128 + col] = (unsigned short)f2bf(acc[nt][j]);
        }
    }
}

// ---------------- MFMA GEMM (bf16 input, layer 1) ----------------
__global__ __launch_bounds__(256) void k_gemm_bf16(const unsigned short* __restrict__ Hb,
                                                   const unsigned short* __restrict__ Wt,
                                                   unsigned short* __restrict__ Tb16, int n) {
    __shared__ char ldsA[64 * 256];
    int t = threadIdx.x;
    int row0 = blockIdx.x * 64;
    int c16 = t & 15;
    int rbase = t >> 4;

    #pragma unroll
    for (int i = 0; i < 4; ++i) {
        int lr = rbase + i * 16;
        int r = row0 + lr;
        uint4 v = make_uint4(0u, 0u, 0u, 0u);
        if (r < n) v = *(const uint4*)(Hb + (size_t)r * 128 + c16 * 8);
        int byte = lr * 256 + c16 * 16;
        *(uint4*)(ldsA + (byte ^ ((lr & 7) << 4))) = v;
    }
    __syncthreads();

    int lane = t & 63;
    int w = t >> 6;
    int rsub = lane & 15;
    int kg = lane >> 4;
    int rowIdx = w * 16 + rsub;
    int abase = rowIdx * 256 + kg * 16;
    int aswz = (rowIdx & 7) << 4;

    f32x4 acc[8];
    #pragma unroll
    for (int nt = 0; nt < 8; ++nt) acc[nt] = (f32x4)(0.f);

    #pragma unroll
    for (int kk = 0; kk < 4; ++kk) {
        bf16x8 a = *(const bf16x8*)(ldsA + ((abase + kk * 64) ^ aswz));
        int k0 = kk * 32 + kg * 8;
        #pragma unroll
        for (int nt = 0; nt < 8; ++nt) {
            int col = nt * 16 + rsub;
            bf16x8 b = *(const bf16x8*)(Wt + col * 128 + k0);
            acc[nt] = __builtin_amdgcn_mfma_f32_16x16x32_bf16(a, b, acc[nt], 0, 0, 0);
        }
    }

    #pragma unroll
    for (int nt = 0; nt < 8; ++nt) {
        #pragma unroll
        for (int j = 0; j < 4; ++j) {
            int row = row0 + w * 16 + kg * 4 + j;
            int col = nt * 16 + rsub;
            if (row < n) Tb16[(size_t)row * 128 + col] = (unsigned short)f2bf(acc[nt][j]);
        }
    }
}

// ---------------- MFMA GEMM 16-wide (layer 2 folded with Wc): T16 f32 = bf16(Hb) @ Wt2c ----------------
__global__ __launch_bounds__(256) void k_gemm16(const unsigned short* __restrict__ Hb,
                                                const unsigned short* __restrict__ Wt2c,
                                                float* __restrict__ T16, int n) {
    __shared__ char ldsA[64 * 256];
    int t = threadIdx.x;
    int row0 = blockIdx.x * 64;
    int c16 = t & 15;
    int rbase = t >> 4;

    #pragma unroll
    for (int i = 0; i < 4; ++i) {
        int lr = rbase + i * 16;
        int r = row0 + lr;
        uint4 v = make_uint4(0u, 0u, 0u, 0u);
        if (r < n) v = *(const uint4*)(Hb + (size_t)r * 128 + c16 * 8);
        int byte = lr * 256 + c16 * 16;
        *(uint4*)(ldsA + (byte ^ ((lr & 7) << 4))) = v;
    }
    __syncthreads();

    int lane = t & 63;
    int w = t >> 6;
    int rsub = lane & 15;
    int kg = lane >> 4;
    int rowIdx = w * 16 + rsub;
    int abase = rowIdx * 256 + kg * 16;
    int aswz = (rowIdx & 7) << 4;

    f32x4 acc = (f32x4)(0.f);
    #pragma unroll
    for (int kk = 0; kk < 4; ++kk) {
        bf16x8 a = *(const bf16x8*)(ldsA + ((abase + kk * 64) ^ aswz));
        int k0 = kk * 32 + kg * 8;
        bf16x8 b = *(const bf16x8*)(Wt2c + rsub * 128 + k0);
        acc = __builtin_amdgcn_mfma_f32_16x16x32_bf16(a, b, acc, 0, 0, 0);
    }

    #pragma unroll
    for (int j = 0; j < 4; ++j) {
        int row = row0 + w * 16 + kg * 4 + j;
        if (row < n) T16[(size_t)row * 16 + rsub] = acc[j];
    }
}

// ---------------- pull aggregation (bf16 gather, f32 acc) -> relu bf16 out ----------------
__global__ __launch_bounds__(256) void k_agg(const unsigned int* __restrict__ Tb,
                                             unsigned int* __restrict__ outB,
                                             const int* __restrict__ rowptr,
                                             const unsigned int* __restrict__ epk,
                                             const float* __restrict__ bias, int n) {
    int wid = (blockIdx.x * 256 + threadIdx.x) >> 6;
    int lane = threadIdx.x & 63;
    if (wid >= n) return;
    float2 b2 = ((const float2*)bias)[lane];
    unsigned int us = Tb[(size_t)wid * 64 + lane];
    int start = rowptr[wid];
    int deg = rowptr[wid + 1] - start;
    float sn = 1.0f / (float)(deg + 1);
    float2 acc;
    acc.x = fmaf(bf2f_lo(us), sn, b2.x);
    acc.y = fmaf(bf2f_hi(us), sn, b2.y);

    for (int j0 = 0; j0 < deg; j0 += 64) {
        int myj = j0 + lane;
        unsigned int rec = 0;
        if (myj < deg) rec = epk[start + myj];
        int m = min(64, deg - j0);
        int jj = 0;
        for (; jj + 16 <= m; jj += 16) {
            unsigned int rr[16], uu[16];
            #pragma unroll
            for (int k = 0; k < 16; ++k) rr[k] = (unsigned int)__shfl((int)rec, jj + k);
            #pragma unroll
            for (int k = 0; k < 16; ++k) uu[k] = Tb[(size_t)(rr[k] & 0xFFFFu) * 64 + lane];
            #pragma unroll
            for (int k = 0; k < 16; ++k) {
                float wk = __half2float(__ushort_as_half((unsigned short)(rr[k] >> 16)));
                acc.x = fmaf(wk, bf2f_lo(uu[k]), acc.x);
                acc.y = fmaf(wk, bf2f_hi(uu[k]), acc.y);
            }
        }
        for (; jj + 4 <= m; jj += 4) {
            unsigned int rr[4], uu[4];
            #pragma unroll
            for (int k = 0; k < 4; ++k) rr[k] = (unsigned int)__shfl((int)rec, jj + k);
            #pragma unroll
            for (int k = 0; k < 4; ++k) uu[k] = Tb[(size_t)(rr[k] & 0xFFFFu) * 64 + lane];
            #pragma unroll
            for (int k = 0; k < 4; ++k) {
                float wk = __half2float(__ushort_as_half((unsigned short)(rr[k] >> 16)));
                acc.x = fmaf(wk, bf2f_lo(uu[k]), acc.x);
                acc.y = fmaf(wk, bf2f_hi(uu[k]), acc.y);
            }
        }
        for (; jj < m; ++jj) {
            unsigned int rj = (unsigned int)__shfl((int)rec, jj);
            unsigned int u = Tb[(size_t)(rj & 0xFFFFu) * 64 + lane];
            float wj = __half2float(__ushort_as_half((unsigned short)(rj >> 16)));
            acc.x = fmaf(wj, bf2f_lo(u), acc.x);
            acc.y = fmaf(wj, bf2f_hi(u), acc.y);
        }
    }

    float rx = fmaxf(acc.x, 0.f), ry = fmaxf(acc.y, 0.f);
    outB[(size_t)wid * 64 + lane] = f2bf(rx) | (f2bf(ry) << 16);
}

// ---------------- 16-wide pull aggregation (f32 L2-resident table, 64B rows) ----------------
// one wave per node: p = lane&15 (feature), q = lane>>4 (edge group mod 4).
__global__ __launch_bounds__(256) void k_agg16(const float* __restrict__ T16,
                                               float* __restrict__ G16,
                                               const int* __restrict__ rowptr,
                                               const unsigned int* __restrict__ epk, int n) {
    int wid = (blockIdx.x * 256 + threadIdx.x) >> 6;
    int lane = threadIdx.x & 63;
    if (wid >= n) return;
    int p = lane & 15;
    int q = lane >> 4;
    int start = rowptr[wid];
    int deg = rowptr[wid + 1] - start;

    float acc = 0.f;
    if (q == 0) {
        float sn = 1.0f / (float)(deg + 1);
        acc = T16[(size_t)wid * 16 + p] * sn;
    }

    for (int j0 = 0; j0 < deg; j0 += 64) {
        int myj = j0 + lane;
        unsigned int rec = 0;
        if (myj < deg) rec = epk[start + myj];
        int m = min(64, deg - j0);
        int mg = (m - q + 3) >> 2;          // edges for group q (m>=1, q<=3)
        int jj = 0;
        for (; jj + 8 <= mg; jj += 8) {
            unsigned int rr[8]; float uu[8];
            #pragma unroll
            for (int k = 0; k < 8; ++k) rr[k] = (unsigned int)__shfl((int)rec, 4 * (jj + k) + q);
            #pragma unroll
            for (int k = 0; k < 8; ++k) uu[k] = T16[(size_t)(rr[k] & 0xFFFFu) * 16 + p];
            #pragma unroll
            for (int k = 0; k < 8; ++k) {
                float wk = __half2float(__ushort_as_half((unsigned short)(rr[k] >> 16)));
                acc = fmaf(wk, uu[k], acc);
            }
        }
        for (; jj < mg; ++jj) {
            unsigned int rj = (unsigned int)__shfl((int)rec, 4 * jj + q);
            float u = T16[(size_t)(rj & 0xFFFFu) * 16 + p];
            float wj = __half2float(__ushort_as_half((unsigned short)(rj >> 16)));
            acc = fmaf(wj, u, acc);
        }
    }

    // combine the 4 edge groups
    acc += __shfl_xor(acc, 16);
    acc += __shfl_xor(acc, 32);

    if (q == 0) G16[(size_t)wid * 16 + p] = acc;
}

// ---------------- pooling (16-wide): segment-sum over sorted batch ids ----------------
// one wave per 64-node chunk; p = lane&15 feature, q = lane>>4 node subgroup (stride 4)
__global__ __launch_bounds__(256) void k_pool16(const float* __restrict__ G16,
                                                const int* __restrict__ batch,
                                                float* pooled, float* cnt, int n) {
    int gw = (blockIdx.x * 256 + threadIdx.x) >> 6;
    int lane = threadIdx.x & 63;
    int p = lane & 15;
    int q = lane >> 4;
    int n0 = gw * 64;
    if (n0 >= n) return;
    int n1 = min(n0 + 64, n);
    int i0 = n0 + q;
    if (i0 >= n1) return;
    int gprev = batch[i0];
    float acc = 0.f;
    float runc = 0.f;
    for (int i = i0; i < n1; i += 4) {
        int g = batch[i];
        if (g != gprev) {               // uniform within the 16-lane subgroup
            atomicAdd(&pooled[gprev * NCLS + p], acc);
            if (p == 0) atomicAdd(&cnt[gprev], runc);
            acc = 0.f; runc = 0.f; gprev = g;
        }
        acc += G16[(size_t)i * 16 + p];
        runc += 1.f;
    }
    atomicAdd(&pooled[gprev * NCLS + p], acc);
    if (p == 0) atomicAdd(&cnt[gprev], runc);
}

// ---------------- head: out[g,c] = pooled[g,c]/cnt[g] + bc2[c] ----------------
__global__ __launch_bounds__(256) void k_head16(const float* __restrict__ pooled,
                                                const float* __restrict__ cnt,
                                                const float* __restrict__ bc2,
                                                float* __restrict__ out) {
    int idx = blockIdx.x * 256 + threadIdx.x;
    if (idx >= NGRAPH * NCLS) return;
    int g = idx >> 4, c = idx & 15;
    float inv = 1.0f / fmaxf(cnt[g], 1.0f);
    out[idx] = pooled[idx] * inv + bc2[c];
}

extern "C" void kernel_launch(void* const* d_in, const int* in_sizes, int n_in,
                              void* d_out, int out_size, void* d_ws, size_t ws_size,
                              hipStream_t stream) {
    const float* x    = (const float*)d_in[0];
    const int*   ei   = (const int*)d_in[1];
    const int*   batch= (const int*)d_in[2];
    const float* W0   = (const float*)d_in[3];
    const float* b0   = (const float*)d_in[4];
    const float* W1   = (const float*)d_in[5];
    const float* b1   = (const float*)d_in[6];
    const float* W2   = (const float*)d_in[7];
    const float* b2   = (const float*)d_in[8];
    const float* Wc   = (const float*)d_in[9];
    const float* bc   = (const float*)d_in[10];
    float* out = (float*)d_out;

    const int N = in_sizes[0] / HID;       // 50000
    const int E = in_sizes[1] / 2;         // 800000
    const int* src = ei;
    const int* dst = ei + E;

    char* p = (char*)d_ws;
    auto alloc = [&](size_t bytes) { void* r = (void*)p; p += (bytes + 255) & ~(size_t)255; return r; };
    int*   counts = (int*)alloc((size_t)N * 4);
    int*   rank   = (int*)alloc((size_t)E * 4);
    int*   csum   = (int*)alloc(256 * 4);
    int*   rowptr = (int*)alloc((size_t)(N + 1) * 4);
    unsigned int* epk = (unsigned int*)alloc((size_t)E * 4);
    float* pooled = (float*)alloc((size_t)NGRAPH * NCLS * 4);
    float* cnt    = (float*)alloc((size_t)NGRAPH * 4);
    unsigned short* Tb16 = (unsigned short*)alloc((size_t)N * HID * 2);
    unsigned short* Hb16 = (unsigned short*)alloc((size_t)N * HID * 2);
    float* T16    = (float*)alloc((size_t)N * NCLS * 4);
    float* G16    = (float*)alloc((size_t)N * NCLS * 4);
    unsigned short* Wt   = (unsigned short*)alloc((size_t)2 * HID * HID * 2);
    unsigned short* Wt2c = (unsigned short*)alloc((size_t)NCLS * 128 * 2);
    float* bc2    = (float*)alloc(NCLS * 4);

    const int NB = (N + CHUNK - 1) / CHUNK;

    k_init<<<(N + 255) / 256, 256, 0, stream>>>(counts, pooled, cnt, W0, W1, Wt, N);
    k_hist<<<(E + 255) / 256, 256, 0, stream>>>(dst, counts, rank, E);
    k_chunksum<<<NB, 256, 0, stream>>>(counts, csum, N);
    k_rowptr<<<NB, 256, 0, stream>>>(counts, csum, rowptr, N, E);
    k_fill<<<(E + 255) / 256, 256, 0, stream>>>(src, dst, rank, counts, rowptr, epk, E);
    k_wc<<<(HID * NCLS + 255) / 256, 256, 0, stream>>>(W2, Wc, b2, bc, Wt2c, bc2);

    const int gemm_grid = (N + 63) / 64;
    const int agg_grid  = ((size_t)N * 64 + 255) / 256;

    // layer 0
    k_gemm_f32<<<gemm_grid, 256, 0, stream>>>(x, Wt, Tb16, N);
    k_agg<<<agg_grid, 256, 0, stream>>>((const unsigned int*)Tb16, (unsigned int*)Hb16,
                                        rowptr, epk, b0, N);
    // layer 1
    k_gemm_bf16<<<gemm_grid, 256, 0, stream>>>(Hb16, Wt + 16384, Tb16, N);
    k_agg<<<agg_grid, 256, 0, stream>>>((const unsigned int*)Tb16, (unsigned int*)Hb16,
                                        rowptr, epk, b1, N);
    // layer 2 folded with classifier: T16 = Hb16 @ (W2@Wc), then 16-wide aggregate
    k_gemm16<<<gemm_grid, 256, 0, stream>>>(Hb16, Wt2c, T16, N);
    k_agg16<<<agg_grid, 256, 0, stream>>>(T16, G16, rowptr, epk, N);

    // pooling + head
    const int pool_blocks = (((N + 63) / 64) * 64 + 255) / 256;
    k_pool16<<<pool_blocks, 256, 0, stream>>>(G16, batch, pooled, cnt, N);
    k_head16<<<(NGRAPH * NCLS + 255) / 256, 256, 0, stream>>>(pooled, cnt, bc2, out);
}